// Round 2
// baseline (358.596 us; speedup 1.0000x reference)
//
#include <hip/hip_runtime.h>
#include <math.h>

#define NQ   8
#define DIMQ 256
#define BB   128
#define TT   64
#define IND  128
#define HID  256
#define CD   384   // comb dim = IND + HID

struct C2 { float x, y; };
__device__ __forceinline__ C2 cmul(C2 a, C2 b) { return {a.x*b.x - a.y*b.y, a.x*b.y + a.y*b.x}; }
__device__ __forceinline__ C2 cadd(C2 a, C2 b) { return {a.x + b.x, a.y + b.y}; }

struct U2 { C2 m00, m01, m10, m11; };

struct Args {
    const float* x;
    const float* W[4];
    const float* bb[4];
    const float* qp[4];
    const float* Uo[4];
    const float* cb[4];
    float* out;
};

// Apply 2x2 complex gate across lanes (qubit bit lives in lane index).
__device__ __forceinline__ void gate_xlane(float (&are)[4], float (&aim)[4],
                                           const U2& u, int bit, int m) {
#pragma unroll
    for (int r = 0; r < 4; ++r) {
        float prx = __shfl_xor(are[r], m);
        float pry = __shfl_xor(aim[r], m);
        C2 me{are[r], aim[r]}, pr{prx, pry};
        C2 us = bit ? u.m11 : u.m00;   // coeff on my amplitude
        C2 up = bit ? u.m10 : u.m01;   // coeff on partner amplitude
        C2 n = cadd(cmul(us, me), cmul(up, pr));
        are[r] = n.x; aim[r] = n.y;
    }
}

// Apply 2x2 complex gate on a register pair (qubit bit lives in register index).
__device__ __forceinline__ void gate_pair(float& r0x, float& r0y, float& r1x, float& r1y,
                                          const U2& u) {
    C2 a0{r0x, r0y}, a1{r1x, r1y};
    C2 n0 = cadd(cmul(u.m00, a0), cmul(u.m01, a1));
    C2 n1 = cadd(cmul(u.m10, a0), cmul(u.m11, a1));
    r0x = n0.x; r0y = n0.y; r1x = n1.x; r1y = n1.y;
}

__global__ __launch_bounds__(256, 1) void qlstm_kernel(Args a) {
    const int b    = blockIdx.x;
    const int tid  = threadIdx.x;
    const int lane = tid & 63;
    const int wv   = tid >> 6;          // wave id == gate id (f,i,g,o)

    __shared__ float Ax[TT][32];        // x-part of all 32 angles, all timesteps (+bias)
    __shared__ float hL[HID];           // recurrent h
    __shared__ C2    angCS[32];         // (cos, sin) of half-angle per (gate,qubit)
    __shared__ U2    ucmb[4][2][8];     // combined RZ*RY*RX per (gate,depth,qubit)
    __shared__ float expL[4][8];        // <Z_q> per gate

    // ---- per-thread register preloads (fixed across timesteps) ----
    // angle-stage role: angle a_ang = tid>>3, partial p = tid&7
    const int a_ang = tid >> 3, p = tid & 7;
    const int g_ang = a_ang >> 3, q_ang = a_ang & 7;
    float wh[32];
    {
        const float* Wg = a.W[g_ang] + q_ang * CD + IND;   // h-part of this W row
#pragma unroll
        for (int i = 0; i < 32; ++i) wh[i] = Wg[i * 8 + p];
    }
    // output-stage role: hidden unit j = tid
    float ur[4][8], cbr[4];
#pragma unroll
    for (int g = 0; g < 4; ++g) {
#pragma unroll
        for (int k = 0; k < 8; ++k) ur[g][k] = a.Uo[g][tid * 8 + k];
        cbr[g] = a.cb[g][tid];
    }

    // ---- combined parameter unitaries (once) ----
    if (tid < 64) {
        int g = tid >> 4, d = (tid >> 3) & 1, q = tid & 7;
        const float* qp = a.qp[g] + q * 6 + d * 3;
        float s0, c0, s1, c1, s2, c2;
        sincosf(0.5f * qp[0], &s0, &c0);
        sincosf(0.5f * qp[1], &s1, &c1);
        sincosf(0.5f * qp[2], &s2, &c2);
        U2 rx = {{c0, 0.f}, {0.f, -s0}, {0.f, -s0}, {c0, 0.f}};
        U2 ry = {{c1, 0.f}, {-s1, 0.f}, {s1, 0.f}, {c1, 0.f}};
        U2 m1 = { cadd(cmul(ry.m00, rx.m00), cmul(ry.m01, rx.m10)),
                  cadd(cmul(ry.m00, rx.m01), cmul(ry.m01, rx.m11)),
                  cadd(cmul(ry.m10, rx.m00), cmul(ry.m11, rx.m10)),
                  cadd(cmul(ry.m10, rx.m01), cmul(ry.m11, rx.m11)) };
        C2 e0 = {c2, -s2}, e1 = {c2, s2};
        ucmb[g][d][q] = { cmul(e0, m1.m00), cmul(e0, m1.m01),
                          cmul(e1, m1.m10), cmul(e1, m1.m11) };
    }

    // ---- x-part of angles for all timesteps (once): Ax[t][a] = x_t . Wx_row + bias ----
    for (int rep = 0; rep < 8; ++rep) {
        int idx = rep * 256 + tid;
        int t = idx >> 5, aa = idx & 31;
        int gg = aa >> 3, qq = aa & 7;
        const float* wrow = a.W[gg] + qq * CD;
        const float* xr   = a.x + (size_t)(t * BB + b) * IND;
        float acc = a.bb[gg][qq];
        for (int e = 0; e < IND; ++e) acc += xr[e] * wrow[e];
        Ax[t][aa] = acc;
    }

    if (tid < HID) hL[tid] = 0.f;
    float creg = 0.f;
    __syncthreads();

    for (int t = 0; t < TT; ++t) {
        // ---- angle stage: ang[a] = Ax[t][a] + h . Wh_row ----
        // NOTE: seed butterfly with h-part ONLY; Ax added once on p==0
        // (previous bug: Ax seeded on all 8 partials -> counted 8x).
        float acc = 0.f;
#pragma unroll
        for (int i = 0; i < 32; ++i) acc += hL[i * 8 + p] * wh[i];
        acc += __shfl_xor(acc, 1);
        acc += __shfl_xor(acc, 2);
        acc += __shfl_xor(acc, 4);
        if (p == 0) {
            float s, c;
            sincosf(0.5f * (acc + Ax[t][a_ang]), &s, &c);
            angCS[a_ang] = {c, s};
        }
        __syncthreads();

        // ---- quantum circuit: wave wv owns gate wv; state = 4 complex amps/lane ----
        // idx = r*64 + lane; qubit q sits at bit pos 7-q (MSB-first like the reference)
        float are[4], aim[4];
        {
            C2 common = {1.f, 0.f};
#pragma unroll
            for (int q = 2; q < 8; ++q) {
                C2 cs = angCS[wv * 8 + q];
                int bit = (lane >> (7 - q)) & 1;
                C2 fq = bit ? C2{0.f, -cs.y} : C2{cs.x, 0.f};
                common = cmul(common, fq);
            }
            C2 cs1 = angCS[wv * 8 + 1], cs0 = angCS[wv * 8 + 0];
#pragma unroll
            for (int r = 0; r < 4; ++r) {
                C2 f1 = (r & 1)  ? C2{0.f, -cs1.y} : C2{cs1.x, 0.f};
                C2 f0 = (r >> 1) ? C2{0.f, -cs0.y} : C2{cs0.x, 0.f};
                C2 amp = cmul(cmul(common, f1), f0);
                are[r] = amp.x; aim[r] = amp.y;
            }
        }

#pragma unroll
        for (int d = 0; d < 2; ++d) {
            // combined 1q rotations (commute across distinct qubits)
            U2 u;
            u = ucmb[wv][d][0];                       // qubit 0: register bit 1
            gate_pair(are[0], aim[0], are[2], aim[2], u);
            gate_pair(are[1], aim[1], are[3], aim[3], u);
            u = ucmb[wv][d][1];                       // qubit 1: register bit 0
            gate_pair(are[0], aim[0], are[1], aim[1], u);
            gate_pair(are[2], aim[2], are[3], aim[3], u);
#pragma unroll
            for (int q = 2; q < 8; ++q) {             // qubits 2..7: lane bits 5..0
                const int pos = 7 - q, m = 1 << pos;
                const int bit = (lane >> pos) & 1;
                u = ucmb[wv][d][q];
                gate_xlane(are, aim, u, bit, m);
            }
            // CNOT chain: (0,1),(1,2),...,(6,7),(7,0)
            { // (0,1): ctrl r-bit1, tgt r-bit0 -> swap regs 2,3
                float tx = are[2], ty = aim[2];
                are[2] = are[3]; aim[2] = aim[3];
                are[3] = tx;     aim[3] = ty;
            }
            { // (1,2): ctrl r-bit0 (r=1,3), tgt lane bit5
                are[1] = __shfl_xor(are[1], 32); aim[1] = __shfl_xor(aim[1], 32);
                are[3] = __shfl_xor(are[3], 32); aim[3] = __shfl_xor(aim[3], 32);
            }
#pragma unroll
            for (int q = 2; q < 7; ++q) {  // (q,q+1): ctrl lane bit (7-q), tgt lane bit (6-q)
                const int cpos = 7 - q, m = 1 << (6 - q);
                const bool ctrl = (lane >> cpos) & 1;
#pragma unroll
                for (int r = 0; r < 4; ++r) {
                    float px = __shfl_xor(are[r], m);
                    float py = __shfl_xor(aim[r], m);
                    are[r] = ctrl ? px : are[r];
                    aim[r] = ctrl ? py : aim[r];
                }
            }
            { // (7,0): ctrl lane bit0, tgt r-bit1 -> swap (r0,r2),(r1,r3) where ctrl
                const bool ctrl = lane & 1;
                float t0x = ctrl ? are[2] : are[0], t0y = ctrl ? aim[2] : aim[0];
                float t2x = ctrl ? are[0] : are[2], t2y = ctrl ? aim[0] : aim[2];
                float t1x = ctrl ? are[3] : are[1], t1y = ctrl ? aim[3] : aim[1];
                float t3x = ctrl ? are[1] : are[3], t3y = ctrl ? aim[1] : aim[3];
                are[0] = t0x; aim[0] = t0y; are[2] = t2x; aim[2] = t2y;
                are[1] = t1x; aim[1] = t1y; are[3] = t3x; aim[3] = t3y;
            }
        }

        // ---- expectation values <Z_q> ----
        float pr[4];
#pragma unroll
        for (int r = 0; r < 4; ++r) pr[r] = are[r] * are[r] + aim[r] * aim[r];
        float P = pr[0] + pr[1] + pr[2] + pr[3];
        float s[8];
        s[0] = pr[0] + pr[1] - pr[2] - pr[3];   // qubit 0: r-bit1
        s[1] = pr[0] - pr[1] + pr[2] - pr[3];   // qubit 1: r-bit0
#pragma unroll
        for (int q = 2; q < 8; ++q) {
            const int pos = 7 - q;
            s[q] = ((lane >> pos) & 1) ? -P : P;
        }
#pragma unroll
        for (int m = 1; m < 64; m <<= 1) {
#pragma unroll
            for (int q = 0; q < 8; ++q) s[q] += __shfl_xor(s[q], m);
        }
        if (lane == 0) {
#pragma unroll
            for (int q = 0; q < 8; ++q) expL[wv][q] = s[q];
        }
        __syncthreads();

        // ---- output projection + LSTM pointwise (thread j = tid) ----
        float og[4];
#pragma unroll
        for (int g = 0; g < 4; ++g) {
            float o = cbr[g];
#pragma unroll
            for (int k = 0; k < 8; ++k) o += expL[g][k] * ur[g][k];
            og[g] = o;
        }
        float fg = 1.f / (1.f + expf(-og[0]));
        float ig = 1.f / (1.f + expf(-og[1]));
        float gg = tanhf(og[2]);
        float oo = 1.f / (1.f + expf(-og[3]));
        creg = fg * creg + ig * gg;
        float h = oo * tanhf(creg);

        hL[tid] = h;
        a.out[(size_t)(t * BB + b) * HID + tid] = h;
        if (t == TT - 1) {
            a.out[(size_t)TT * BB * HID + (size_t)b * HID + tid] = h;
            a.out[(size_t)TT * BB * HID + (size_t)BB * HID + (size_t)b * HID + tid] = creg;
        }
        __syncthreads();
    }
}

extern "C" void kernel_launch(void* const* d_in, const int* in_sizes, int n_in,
                              void* d_out, int out_size, void* d_ws, size_t ws_size,
                              hipStream_t stream) {
    (void)in_sizes; (void)n_in; (void)out_size; (void)d_ws; (void)ws_size;
    Args ar;
    ar.x = (const float*)d_in[0];
    for (int g = 0; g < 4; ++g) {
        ar.W[g]  = (const float*)d_in[1 + 5 * g];
        ar.bb[g] = (const float*)d_in[2 + 5 * g];
        ar.qp[g] = (const float*)d_in[3 + 5 * g];
        ar.Uo[g] = (const float*)d_in[4 + 5 * g];
        ar.cb[g] = (const float*)d_in[5 + 5 * g];
    }
    ar.out = (float*)d_out;
    qlstm_kernel<<<dim3(BB), dim3(256), 0, stream>>>(ar);
}

// Round 3
// 277.805 us; speedup vs baseline: 1.2908x; 1.2908x over previous
//
#include <hip/hip_runtime.h>
#include <math.h>

#define NQ   8
#define BB   128
#define TT   64
#define IND  128
#define HID  256
#define CD   384   // comb dim = IND + HID

struct C2 { float x, y; };
__device__ __forceinline__ C2 cmul(C2 a, C2 b) { return {a.x*b.x - a.y*b.y, a.x*b.y + a.y*b.x}; }
__device__ __forceinline__ C2 cadd(C2 a, C2 b) { return {a.x + b.x, a.y + b.y}; }

struct alignas(16) U2 { C2 m00, m01, m10, m11; };

struct Args {
    const float* x;
    const float* W[4];
    const float* bb[4];
    const float* qp[4];
    const float* Uo[4];
    const float* cb[4];
    float* out;
};

// Fast lane-xor exchange: DPP for 1,2,8 (pure VALU), ds_swizzle for 4,16,
// ds_bpermute fallback (__shfl_xor) for 32.
template<int M>
__device__ __forceinline__ float lx(float v) {
    int i = __float_as_int(v);
    if constexpr (M == 1)
        return __int_as_float(__builtin_amdgcn_update_dpp(i, i, 0xB1, 0xF, 0xF, false)); // quad_perm [1,0,3,2]
    else if constexpr (M == 2)
        return __int_as_float(__builtin_amdgcn_update_dpp(i, i, 0x4E, 0xF, 0xF, false)); // quad_perm [2,3,0,1]
    else if constexpr (M == 4)
        return __int_as_float(__builtin_amdgcn_ds_swizzle(i, 0x101F));                   // xor4
    else if constexpr (M == 8)
        return __int_as_float(__builtin_amdgcn_update_dpp(i, i, 0x128, 0xF, 0xF, false)); // row_ror:8 == xor8
    else if constexpr (M == 16)
        return __int_as_float(__builtin_amdgcn_ds_swizzle(i, 0x401F));                   // xor16
    else
        return __shfl_xor(v, 32);
}

__device__ __forceinline__ float sigm(float x) {
    return __builtin_amdgcn_rcpf(1.f + __expf(-x));
}
__device__ __forceinline__ float tanh_fast(float x) {
    float e = __expf(2.f * x);
    return 1.f - 2.f * __builtin_amdgcn_rcpf(e + 1.f);
}

// 2x2 complex gate across lanes (qubit bit lives in lane index, mask M).
template<int M>
__device__ __forceinline__ void gate_xlaneT(float (&are)[4], float (&aim)[4],
                                            const U2& u, bool bit) {
    float usx = bit ? u.m11.x : u.m00.x, usy = bit ? u.m11.y : u.m00.y;
    float upx = bit ? u.m10.x : u.m01.x, upy = bit ? u.m10.y : u.m01.y;
#pragma unroll
    for (int r = 0; r < 4; ++r) {
        float prx = lx<M>(are[r]);
        float pry = lx<M>(aim[r]);
        float nx = usx * are[r] - usy * aim[r] + upx * prx - upy * pry;
        float ny = usx * aim[r] + usy * are[r] + upx * pry + upy * prx;
        are[r] = nx; aim[r] = ny;
    }
}

// Conditional cross-lane swap (CNOT with lane-bit control and lane-bit target M).
template<int M>
__device__ __forceinline__ void cswapT(float (&are)[4], float (&aim)[4], bool ctrl) {
#pragma unroll
    for (int r = 0; r < 4; ++r) {
        float px = lx<M>(are[r]);
        float py = lx<M>(aim[r]);
        are[r] = ctrl ? px : are[r];
        aim[r] = ctrl ? py : aim[r];
    }
}

// 2x2 complex gate on a register pair (qubit bit lives in register index).
__device__ __forceinline__ void gate_pair(float& r0x, float& r0y, float& r1x, float& r1y,
                                          const U2& u) {
    C2 a0{r0x, r0y}, a1{r1x, r1y};
    C2 n0 = cadd(cmul(u.m00, a0), cmul(u.m01, a1));
    C2 n1 = cadd(cmul(u.m10, a0), cmul(u.m11, a1));
    r0x = n0.x; r0y = n0.y; r1x = n1.x; r1y = n1.y;
}

__device__ __forceinline__ float bcast_lane(float v, int srclane) {
    return __int_as_float(__builtin_amdgcn_readlane(__float_as_int(v), srclane));
}

__global__ __launch_bounds__(256, 1) void qlstm_kernel(Args a) {
    const int b    = blockIdx.x;
    const int tid  = threadIdx.x;
    const int lane = tid & 63;
    const int wv   = tid >> 6;          // wave id == gate id (f,i,g,o)

    __shared__ float Ax[TT][32];        // x-part of all 32 angles, all timesteps (+bias)
    __shared__ float hL[HID];           // recurrent h
    __shared__ U2    ucmb[4][2][8];     // combined RZ*RY*RX per (gate,depth,qubit)
    __shared__ float expL[4][8];        // <Z_q> per gate

    // angle-stage role: angle a_ang = tid>>3, partial p = tid&7
    const int a_ang = tid >> 3, p = tid & 7;
    const int g_ang = a_ang >> 3, q_ang = a_ang & 7;
    float wh[32];
    {
        const float* Wg = a.W[g_ang] + q_ang * CD + IND;   // h-part of this W row
#pragma unroll
        for (int i = 0; i < 32; ++i) wh[i] = Wg[i * 8 + p];
    }
    // output-stage role: hidden unit j = tid
    float ur[4][8], cbr[4];
#pragma unroll
    for (int g = 0; g < 4; ++g) {
#pragma unroll
        for (int k = 0; k < 8; ++k) ur[g][k] = a.Uo[g][tid * 8 + k];
        cbr[g] = a.cb[g][tid];
    }

    // ---- combined parameter unitaries (once) ----
    if (tid < 64) {
        int g = tid >> 4, d = (tid >> 3) & 1, q = tid & 7;
        const float* qp = a.qp[g] + q * 6 + d * 3;
        float s0, c0, s1, c1, s2, c2;
        sincosf(0.5f * qp[0], &s0, &c0);
        sincosf(0.5f * qp[1], &s1, &c1);
        sincosf(0.5f * qp[2], &s2, &c2);
        U2 rx = {{c0, 0.f}, {0.f, -s0}, {0.f, -s0}, {c0, 0.f}};
        U2 ry = {{c1, 0.f}, {-s1, 0.f}, {s1, 0.f}, {c1, 0.f}};
        U2 m1 = { cadd(cmul(ry.m00, rx.m00), cmul(ry.m01, rx.m10)),
                  cadd(cmul(ry.m00, rx.m01), cmul(ry.m01, rx.m11)),
                  cadd(cmul(ry.m10, rx.m00), cmul(ry.m11, rx.m10)),
                  cadd(cmul(ry.m10, rx.m01), cmul(ry.m11, rx.m11)) };
        C2 e0 = {c2, -s2}, e1 = {c2, s2};
        ucmb[g][d][q] = { cmul(e0, m1.m00), cmul(e0, m1.m01),
                          cmul(e1, m1.m10), cmul(e1, m1.m11) };
    }

    // ---- x-part of angles for all timesteps (once): Ax[t][a] = x_t . Wx_row + bias ----
    for (int rep = 0; rep < 8; ++rep) {
        int idx = rep * 256 + tid;
        int t = idx >> 5, aa = idx & 31;
        int gg = aa >> 3, qq = aa & 7;
        const float* wrow = a.W[gg] + qq * CD;
        const float* xr   = a.x + (size_t)(t * BB + b) * IND;
        float acc = a.bb[gg][qq];
        for (int e = 0; e < IND; ++e) acc += xr[e] * wrow[e];
        Ax[t][aa] = acc;
    }

    if (tid < HID) hL[tid] = 0.f;
    float creg = 0.f;
    __syncthreads();

    for (int t = 0; t < TT; ++t) {
        // ---- angle stage (wave-local: wave wv computes its own 8 angles) ----
        float ac0 = 0.f, ac1 = 0.f;
#pragma unroll
        for (int i = 0; i < 32; i += 2) {
            ac0 += hL[i * 8 + p] * wh[i];
            ac1 += hL[(i + 1) * 8 + p] * wh[i + 1];
        }
        float acc = ac0 + ac1;
        acc += lx<1>(acc);
        acc += lx<2>(acc);
        acc += lx<4>(acc);
        float ang = 0.5f * (acc + Ax[t][a_ang]);
        float cA = __cosf(ang), sA = __sinf(ang);   // all lanes, no divergence
        // broadcast the wave's 8 (c,s) pairs into SGPRs
        float cs_c[8], cs_s[8];
#pragma unroll
        for (int q = 0; q < 8; ++q) {
            cs_c[q] = bcast_lane(cA, q * 8);
            cs_s[q] = bcast_lane(sA, q * 8);
        }

        // ---- quantum circuit: state = 4 complex amps/lane; qubit q at bit 7-q ----
        float are[4], aim[4];
        {
            float comx = 1.f, comy = 0.f;
#pragma unroll
            for (int q = 2; q < 8; ++q) {
                int bit = (lane >> (7 - q)) & 1;
                float fx = bit ? 0.f : cs_c[q];
                float fy = bit ? -cs_s[q] : 0.f;
                float nx = comx * fx - comy * fy;
                float ny = comx * fy + comy * fx;
                comx = nx; comy = ny;
            }
#pragma unroll
            for (int r = 0; r < 4; ++r) {
                float f1x = (r & 1)  ? 0.f : cs_c[1], f1y = (r & 1)  ? -cs_s[1] : 0.f;
                float f0x = (r >> 1) ? 0.f : cs_c[0], f0y = (r >> 1) ? -cs_s[0] : 0.f;
                float t1x = comx * f1x - comy * f1y, t1y = comx * f1y + comy * f1x;
                are[r] = t1x * f0x - t1y * f0y;
                aim[r] = t1x * f0y + t1y * f0x;
            }
        }

#pragma unroll
        for (int d = 0; d < 2; ++d) {
            U2 u;
            u = ucmb[wv][d][0];                       // qubit 0: register bit 1
            gate_pair(are[0], aim[0], are[2], aim[2], u);
            gate_pair(are[1], aim[1], are[3], aim[3], u);
            u = ucmb[wv][d][1];                       // qubit 1: register bit 0
            gate_pair(are[0], aim[0], are[1], aim[1], u);
            gate_pair(are[2], aim[2], are[3], aim[3], u);
            gate_xlaneT<32>(are, aim, ucmb[wv][d][2], (lane >> 5) & 1);
            gate_xlaneT<16>(are, aim, ucmb[wv][d][3], (lane >> 4) & 1);
            gate_xlaneT< 8>(are, aim, ucmb[wv][d][4], (lane >> 3) & 1);
            gate_xlaneT< 4>(are, aim, ucmb[wv][d][5], (lane >> 2) & 1);
            gate_xlaneT< 2>(are, aim, ucmb[wv][d][6], (lane >> 1) & 1);
            gate_xlaneT< 1>(are, aim, ucmb[wv][d][7], lane & 1);
            // CNOT chain: (0,1),(1,2),...,(6,7),(7,0)
            { // (0,1): ctrl r-bit1, tgt r-bit0 -> swap regs 2,3
                float tx = are[2], ty = aim[2];
                are[2] = are[3]; aim[2] = aim[3];
                are[3] = tx;     aim[3] = ty;
            }
            { // (1,2): ctrl r-bit0 (r=1,3), tgt lane bit5
                are[1] = lx<32>(are[1]); aim[1] = lx<32>(aim[1]);
                are[3] = lx<32>(are[3]); aim[3] = lx<32>(aim[3]);
            }
            cswapT<16>(are, aim, (lane >> 5) & 1);    // (2,3)
            cswapT< 8>(are, aim, (lane >> 4) & 1);    // (3,4)
            cswapT< 4>(are, aim, (lane >> 3) & 1);    // (4,5)
            cswapT< 2>(are, aim, (lane >> 2) & 1);    // (5,6)
            cswapT< 1>(are, aim, (lane >> 1) & 1);    // (6,7)
            { // (7,0): ctrl lane bit0, tgt r-bit1 -> swap (r0,r2),(r1,r3) where ctrl
                const bool ctrl = lane & 1;
                float t0x = ctrl ? are[2] : are[0], t0y = ctrl ? aim[2] : aim[0];
                float t2x = ctrl ? are[0] : are[2], t2y = ctrl ? aim[0] : aim[2];
                float t1x = ctrl ? are[3] : are[1], t1y = ctrl ? aim[3] : aim[1];
                float t3x = ctrl ? are[1] : are[3], t3y = ctrl ? aim[1] : aim[3];
                are[0] = t0x; aim[0] = t0y; are[2] = t2x; aim[2] = t2y;
                are[1] = t1x; aim[1] = t1y; are[3] = t3x; aim[3] = t3y;
            }
        }

        // ---- expectation values <Z_q> ----
        float pr[4];
#pragma unroll
        for (int r = 0; r < 4; ++r) pr[r] = are[r] * are[r] + aim[r] * aim[r];
        float P = pr[0] + pr[1] + pr[2] + pr[3];
        float s[8];
        s[0] = pr[0] + pr[1] - pr[2] - pr[3];   // qubit 0: r-bit1
        s[1] = pr[0] - pr[1] + pr[2] - pr[3];   // qubit 1: r-bit0
#pragma unroll
        for (int q = 2; q < 8; ++q) {
            const int pos = 7 - q;
            s[q] = ((lane >> pos) & 1) ? -P : P;
        }
#pragma unroll
        for (int q = 0; q < 8; ++q) s[q] += lx<1>(s[q]);
#pragma unroll
        for (int q = 0; q < 8; ++q) s[q] += lx<2>(s[q]);
#pragma unroll
        for (int q = 0; q < 8; ++q) s[q] += lx<4>(s[q]);
#pragma unroll
        for (int q = 0; q < 8; ++q) s[q] += lx<8>(s[q]);
#pragma unroll
        for (int q = 0; q < 8; ++q) s[q] += lx<16>(s[q]);
#pragma unroll
        for (int q = 0; q < 8; ++q) s[q] += __shfl_xor(s[q], 32);
        if (lane == 0) {
#pragma unroll
            for (int q = 0; q < 8; ++q) expL[wv][q] = s[q];
        }
        __syncthreads();   // expL visible to all waves

        // ---- output projection + LSTM pointwise (thread j = tid) ----
        float og[4];
#pragma unroll
        for (int g = 0; g < 4; ++g) {
            float o = cbr[g];
#pragma unroll
            for (int k = 0; k < 8; ++k) o += expL[g][k] * ur[g][k];
            og[g] = o;
        }
        float fg = sigm(og[0]);
        float ig = sigm(og[1]);
        float gg = tanh_fast(og[2]);
        float oo = sigm(og[3]);
        creg = fg * creg + ig * gg;
        float h = oo * tanh_fast(creg);

        hL[tid] = h;
        a.out[(size_t)(t * BB + b) * HID + tid] = h;
        if (t == TT - 1) {
            a.out[(size_t)TT * BB * HID + (size_t)b * HID + tid] = h;
            a.out[(size_t)TT * BB * HID + (size_t)BB * HID + (size_t)b * HID + tid] = creg;
        }
        __syncthreads();   // hL visible for next step's angle stage
    }
}

extern "C" void kernel_launch(void* const* d_in, const int* in_sizes, int n_in,
                              void* d_out, int out_size, void* d_ws, size_t ws_size,
                              hipStream_t stream) {
    (void)in_sizes; (void)n_in; (void)out_size; (void)d_ws; (void)ws_size;
    Args ar;
    ar.x = (const float*)d_in[0];
    for (int g = 0; g < 4; ++g) {
        ar.W[g]  = (const float*)d_in[1 + 5 * g];
        ar.bb[g] = (const float*)d_in[2 + 5 * g];
        ar.qp[g] = (const float*)d_in[3 + 5 * g];
        ar.Uo[g] = (const float*)d_in[4 + 5 * g];
        ar.cb[g] = (const float*)d_in[5 + 5 * g];
    }
    ar.out = (float*)d_out;
    qlstm_kernel<<<dim3(BB), dim3(256), 0, stream>>>(ar);
}

// Round 8
// 244.113 us; speedup vs baseline: 1.4690x; 1.1380x over previous
//
#include <hip/hip_runtime.h>
#include <math.h>

#define BB   128
#define TT   64
#define IND  128
#define HID  256
#define CD   384   // comb dim = IND + HID

struct C2 { float x, y; };
__device__ __forceinline__ C2 cmul(C2 a, C2 b) { return {a.x*b.x - a.y*b.y, a.x*b.y + a.y*b.x}; }
__device__ __forceinline__ C2 cadd(C2 a, C2 b) { return {a.x + b.x, a.y + b.y}; }
__device__ __forceinline__ C2 csub(C2 a, C2 b) { return {a.x - b.x, a.y - b.y}; }
__device__ __forceinline__ C2 conjc(C2 a) { return {a.x, -a.y}; }

struct Args {
    const float* x;
    const float* W[4];
    const float* bb[4];
    const float* qp[4];
    const float* Uo[4];
    const float* cb[4];
    float* out;
};

template<int CTRL>
__device__ __forceinline__ int dppmv(int v) {
    return __builtin_amdgcn_update_dpp(v, v, CTRL, 0xF, 0xF, false);
}

// Lane-xor exchange. ALL primitives below are hardware-proven in the R3
// passing run (365->278us kernel):
//  1,2: quad_perm DPP; 8: row_ror:8 DPP; 4: ds_swizzle xor4; 16: ds_swizzle
//  xor16; 32: __shfl_xor (ds_bpermute).
//  R4's DPP row_shl/row_shr pair for xor4 is the prime suspect for the
//  persistent 0.22 error (undocumented shift direction) -> reverted.
//  v_permlane{16,32}_swap semantics unproven (R5/R6) -> abandoned.
template<int M>
__device__ __forceinline__ float lx(float v) {
    int i = __float_as_int(v);
    if constexpr (M == 1)
        return __int_as_float(dppmv<0xB1>(i));            // quad_perm [1,0,3,2]
    else if constexpr (M == 2)
        return __int_as_float(dppmv<0x4E>(i));            // quad_perm [2,3,0,1]
    else if constexpr (M == 4)
        return __int_as_float(__builtin_amdgcn_ds_swizzle(i, 0x101F));  // xor4 (proven R3)
    else if constexpr (M == 8)
        return __int_as_float(dppmv<0x128>(i));           // row_ror:8 == xor8 (proven R3)
    else if constexpr (M == 16)
        return __int_as_float(__builtin_amdgcn_ds_swizzle(i, 0x401F));  // xor16 (proven R3)
    else
        return __shfl_xor(v, 32);                         // ds_bpermute (proven R2/R3)
}

__device__ __forceinline__ float rfl(float v) {
    return __int_as_float(__builtin_amdgcn_readfirstlane(__float_as_int(v)));
}
__device__ __forceinline__ float bcast_lane(float v, int srclane) {
    return __int_as_float(__builtin_amdgcn_readlane(__float_as_int(v), srclane));
}
__device__ __forceinline__ float sigm(float x) {
    return __builtin_amdgcn_rcpf(1.f + __expf(-x));
}
__device__ __forceinline__ float tanh_fast(float x) {
    float e = __expf(2.f * x);
    return 1.f - 2.f * __builtin_amdgcn_rcpf(e + 1.f);
}

// SU(2) gate on a lane-bit qubit; u = {ax, ay(sign-baked), bx(sign-baked), by}.
template<int M>
__device__ __forceinline__ void gate_lane(float (&are)[4], float (&aim)[4], const float* u) {
#pragma unroll
    for (int r = 0; r < 4; ++r) {
        float px = lx<M>(are[r]);
        float py = lx<M>(aim[r]);
        float nx = u[0]*are[r] - u[1]*aim[r] + u[2]*px - u[3]*py;
        float ny = u[0]*aim[r] + u[1]*are[r] + u[2]*py + u[3]*px;
        are[r] = nx; aim[r] = ny;
    }
}

// SU(2) gate on a register-bit qubit pair: n0 = a*A0 + b*A1; n1 = -conj(b)*A0 + conj(a)*A1.
__device__ __forceinline__ void gate_pair2(float& a0x, float& a0y, float& a1x, float& a1y,
                                           float ax, float ay, float bx, float by) {
    float n0x = ax*a0x - ay*a0y + bx*a1x - by*a1y;
    float n0y = ax*a0y + ay*a0x + bx*a1y + by*a1x;
    float n1x = -bx*a0x - by*a0y + ax*a1x + ay*a1y;
    float n1y = -bx*a0y + by*a0x + ax*a1y - ay*a1x;
    a0x = n0x; a0y = n0y; a1x = n1x; a1y = n1y;
}

template<int M>
__device__ __forceinline__ void cswapT(float (&are)[4], float (&aim)[4], bool ctrl) {
#pragma unroll
    for (int r = 0; r < 4; ++r) {
        float px = lx<M>(are[r]);
        float py = lx<M>(aim[r]);
        are[r] = ctrl ? px : are[r];
        aim[r] = ctrl ? py : aim[r];
    }
}

__global__ __launch_bounds__(256, 1) void qlstm_kernel(Args a) {
    const int b    = blockIdx.x;
    const int tid  = threadIdx.x;
    const int lane = tid & 63;
    const int wv   = tid >> 6;          // wave id == gate id (f,i,g,o)

    __shared__ float Ax[TT][32];                       // x-part of angles (+bias), all t
    __shared__ __align__(16) float hH[16][HID];        // h history ring (flushed /16 steps)
    __shared__ __align__(16) float4 uab[4][2][8];      // SU(2) (ax,ay,bx,by) per gate
    __shared__ __align__(16) float expL[32];           // <Z_q> all 4 gates

    // ---- angle-stage role: angle a_ang = tid>>3, partial p = tid&7 covers 32 contig h ----
    const int a_ang = tid >> 3, p = tid & 7;
    const int g_ang = a_ang >> 3, q_ang = a_ang & 7;
    float whr[8][4];
    {
        const float* Wg = a.W[g_ang] + q_ang * CD + IND;   // h-part of this W row
#pragma unroll
        for (int k = 0; k < 8; ++k) {
            int base = p * 32 + ((4 * (k + p)) & 31);      // staggered: conflict-free b128
#pragma unroll
            for (int j = 0; j < 4; ++j) whr[k][j] = Wg[base + j];
        }
    }
    // ---- output-stage role: hidden unit j = tid ----
    float ur[4][8], cbr[4];
#pragma unroll
    for (int g = 0; g < 4; ++g) {
#pragma unroll
        for (int k = 0; k < 8; ++k) ur[g][k] = a.Uo[g][tid * 8 + k];
        cbr[g] = a.cb[g][tid];
    }

    // ---- SU(2) parameter unitaries alpha,beta = Rz*Ry*Rx (once) ----
    if (tid < 64) {
        int g = tid >> 4, d = (tid >> 3) & 1, q = tid & 7;
        const float* qp = a.qp[g] + q * 6 + d * 3;
        float s0, c0, s1, c1, s2, c2;
        sincosf(0.5f * qp[0], &s0, &c0);
        sincosf(0.5f * qp[1], &s1, &c1);
        sincosf(0.5f * qp[2], &s2, &c2);
        C2 aX{c0, 0.f}, bX{0.f, -s0};          // Rx
        C2 aY{c1, 0.f}, bY{-s1, 0.f};          // Ry
        C2 aB = csub(cmul(aY, aX), cmul(bY, conjc(bX)));   // Ry∘Rx
        C2 bB = cadd(cmul(aY, bX), cmul(bY, conjc(aX)));
        C2 aZ{c2, -s2};                         // Rz (beta=0)
        C2 al = cmul(aZ, aB), be = cmul(aZ, bB);
        uab[g][d][q] = make_float4(al.x, al.y, be.x, be.y);
    }

    // ---- x-part of angles for all timesteps (once) ----
    for (int rep = 0; rep < 8; ++rep) {
        int idx = rep * 256 + tid;
        int t = idx >> 5, aa = idx & 31;
        int gg = aa >> 3, qq = aa & 7;
        const float4* w4 = (const float4*)(a.W[gg] + qq * CD);
        const float4* x4 = (const float4*)(a.x + (size_t)(t * BB + b) * IND);
        float acc = a.bb[gg][qq];
        for (int e = 0; e < IND / 4; ++e) {
            float4 xv = x4[e], wvv = w4[e];
            acc += xv.x * wvv.x + xv.y * wvv.y + xv.z * wvv.z + xv.w * wvv.w;
        }
        Ax[t][aa] = acc;
    }

    hH[15][tid] = 0.f;                  // h_{-1} = 0 lives at ring row 15
    float creg = 0.f, h = 0.f;
    __syncthreads();

    // ---- bake per-wave unitaries into registers (lane-bit signs applied) ----
    float gA[2][6][4];                  // 48 VGPR: qubits 2..7 (lane bits 5..0)
#pragma unroll
    for (int d = 0; d < 2; ++d)
#pragma unroll
    for (int qi = 0; qi < 6; ++qi) {
        float4 u = uab[wv][d][qi + 2];
        bool bit = (lane >> (5 - qi)) & 1;
        gA[d][qi][0] = u.x;
        gA[d][qi][1] = bit ? -u.y : u.y;
        gA[d][qi][2] = bit ? -u.z : u.z;
        gA[d][qi][3] = u.w;
    }
    float qr[2][2][4];                  // SGPRs: qubits 0,1 (register bits)
#pragma unroll
    for (int d = 0; d < 2; ++d) {
        float4 u0 = uab[wv][d][0], u1 = uab[wv][d][1];
        qr[0][d][0] = rfl(u0.x); qr[0][d][1] = rfl(u0.y);
        qr[0][d][2] = rfl(u0.z); qr[0][d][3] = rfl(u0.w);
        qr[1][d][0] = rfl(u1.x); qr[1][d][1] = rfl(u1.y);
        qr[1][d][2] = rfl(u1.z); qr[1][d][3] = rfl(u1.w);
    }

    for (int t = 0; t < TT; ++t) {
        // ---- angle stage: wave-local; staggered float4 LDS reads, no bank conflicts ----
        const int rowPrev = (t + 15) & 15;
        const float* hrow = hH[rowPrev];
        float ac0 = 0.f, ac1 = 0.f;
#pragma unroll
        for (int k = 0; k < 8; ++k) {
            int base = p * 32 + ((4 * (k + p)) & 31);
            const float4 hv = *reinterpret_cast<const float4*>(&hrow[base]);
            if (k & 1) { ac1 += hv.x*whr[k][0] + hv.y*whr[k][1] + hv.z*whr[k][2] + hv.w*whr[k][3]; }
            else       { ac0 += hv.x*whr[k][0] + hv.y*whr[k][1] + hv.z*whr[k][2] + hv.w*whr[k][3]; }
        }
        float acc = ac0 + ac1;
        acc += lx<1>(acc);
        acc += lx<2>(acc);
        acc += lx<4>(acc);
        float ang = 0.5f * (acc + Ax[t][a_ang]);
        float cA = __cosf(ang), sA = __sinf(ang);
        float cs_c[8], cs_s[8];
#pragma unroll
        for (int q = 0; q < 8; ++q) {
            cs_c[q] = bcast_lane(cA, q * 8);
            cs_s[q] = bcast_lane(sA, q * 8);
        }

        // ---- product-state init: amp = prod_q f_q, tree-multiplied ----
        float are[4], aim[4];
        {
            C2 f[6];
#pragma unroll
            for (int qi = 0; qi < 6; ++qi) {
                bool bit = (lane >> (5 - qi)) & 1;
                f[qi].x = bit ? 0.f : cs_c[qi + 2];
                f[qi].y = bit ? -cs_s[qi + 2] : 0.f;
            }
            C2 c01 = cmul(f[0], f[1]);
            C2 c23 = cmul(f[2], f[3]);
            C2 c45 = cmul(f[4], f[5]);
            C2 com = cmul(cmul(c01, c23), c45);
#pragma unroll
            for (int r = 0; r < 4; ++r) {
                float f1x = (r & 1)  ? 0.f : cs_c[1], f1y = (r & 1)  ? -cs_s[1] : 0.f;
                float f0x = (r >> 1) ? 0.f : cs_c[0], f0y = (r >> 1) ? -cs_s[0] : 0.f;
                C2 t1 = cmul(com, {f1x, f1y});
                are[r] = t1.x * f0x - t1.y * f0y;
                aim[r] = t1.x * f0y + t1.y * f0x;
            }
        }

        // ---- circuit: 2 depths ----
#pragma unroll
        for (int d = 0; d < 2; ++d) {
            gate_pair2(are[0], aim[0], are[2], aim[2], qr[0][d][0], qr[0][d][1], qr[0][d][2], qr[0][d][3]);
            gate_pair2(are[1], aim[1], are[3], aim[3], qr[0][d][0], qr[0][d][1], qr[0][d][2], qr[0][d][3]);
            gate_pair2(are[0], aim[0], are[1], aim[1], qr[1][d][0], qr[1][d][1], qr[1][d][2], qr[1][d][3]);
            gate_pair2(are[2], aim[2], are[3], aim[3], qr[1][d][0], qr[1][d][1], qr[1][d][2], qr[1][d][3]);
            gate_lane<32>(are, aim, gA[d][0]);
            gate_lane<16>(are, aim, gA[d][1]);
            gate_lane< 8>(are, aim, gA[d][2]);
            gate_lane< 4>(are, aim, gA[d][3]);
            gate_lane< 2>(are, aim, gA[d][4]);
            gate_lane< 1>(are, aim, gA[d][5]);
            // CNOT chain: (0,1),(1,2),...,(6,7),(7,0)
            { float tx = are[2], ty = aim[2];
              are[2] = are[3]; aim[2] = aim[3]; are[3] = tx; aim[3] = ty; }
            { are[1] = lx<32>(are[1]); aim[1] = lx<32>(aim[1]);
              are[3] = lx<32>(are[3]); aim[3] = lx<32>(aim[3]); }
            cswapT<16>(are, aim, (lane >> 5) & 1);
            cswapT< 8>(are, aim, (lane >> 4) & 1);
            cswapT< 4>(are, aim, (lane >> 3) & 1);
            cswapT< 2>(are, aim, (lane >> 2) & 1);
            cswapT< 1>(are, aim, (lane >> 1) & 1);
            { const bool ctrl = lane & 1;
              float t0x = ctrl ? are[2] : are[0], t0y = ctrl ? aim[2] : aim[0];
              float t2x = ctrl ? are[0] : are[2], t2y = ctrl ? aim[0] : aim[2];
              float t1x = ctrl ? are[3] : are[1], t1y = ctrl ? aim[3] : aim[1];
              float t3x = ctrl ? are[1] : are[3], t3y = ctrl ? aim[1] : aim[3];
              are[0] = t0x; aim[0] = t0y; are[2] = t2x; aim[2] = t2y;
              are[1] = t1x; aim[1] = t1y; are[3] = t3x; aim[3] = t3y; }
        }

        // ---- expvals: multi-output Walsh butterfly (lane 0 ends correct) ----
        float pr[4];
#pragma unroll
        for (int r = 0; r < 4; ++r) pr[r] = are[r]*are[r] + aim[r]*aim[r];
        float s0 = pr[0] + pr[1] - pr[2] - pr[3];   // qubit 0 (reg bit 1)
        float s1 = pr[0] - pr[1] + pr[2] - pr[3];   // qubit 1 (reg bit 0)
        float T  = pr[0] + pr[1] + pr[2] + pr[3];
        float s2, s3, s4, s5, s6, s7;
        { float pT = lx<1>(T);  s7 = T - pT; T += pT;
          s0 += lx<1>(s0); s1 += lx<1>(s1); }
        { float pT = lx<2>(T);  s6 = T - pT; T += pT;
          s0 += lx<2>(s0); s1 += lx<2>(s1); s7 += lx<2>(s7); }
        { float pT = lx<4>(T);  s5 = T - pT; T += pT;
          s0 += lx<4>(s0); s1 += lx<4>(s1); s7 += lx<4>(s7); s6 += lx<4>(s6); }
        { float pT = lx<8>(T);  s4 = T - pT; T += pT;
          s0 += lx<8>(s0); s1 += lx<8>(s1); s7 += lx<8>(s7); s6 += lx<8>(s6); s5 += lx<8>(s5); }
        { float pT = lx<16>(T); s3 = T - pT; T += pT;
          s0 += lx<16>(s0); s1 += lx<16>(s1); s7 += lx<16>(s7); s6 += lx<16>(s6); s5 += lx<16>(s5); s4 += lx<16>(s4); }
        { float pT = lx<32>(T); s2 = T - pT;
          s0 += lx<32>(s0); s1 += lx<32>(s1); s7 += lx<32>(s7); s6 += lx<32>(s6); s5 += lx<32>(s5); s4 += lx<32>(s4); s3 += lx<32>(s3); }
        if (lane == 0) {
            expL[wv*8 + 0] = s0; expL[wv*8 + 1] = s1; expL[wv*8 + 2] = s2; expL[wv*8 + 3] = s3;
            expL[wv*8 + 4] = s4; expL[wv*8 + 5] = s5; expL[wv*8 + 6] = s6; expL[wv*8 + 7] = s7;
        }
        __syncthreads();

        // ---- output projection + LSTM pointwise (thread j = tid) ----
        const float4* eL = (const float4*)expL;
        float og[4];
#pragma unroll
        for (int g = 0; g < 4; ++g) {
            float4 e0 = eL[g*2], e1 = eL[g*2 + 1];
            og[g] = cbr[g]
                  + e0.x*ur[g][0] + e0.y*ur[g][1] + e0.z*ur[g][2] + e0.w*ur[g][3]
                  + e1.x*ur[g][4] + e1.y*ur[g][5] + e1.z*ur[g][6] + e1.w*ur[g][7];
        }
        float fg = sigm(og[0]);
        float ig = sigm(og[1]);
        float gg = tanh_fast(og[2]);
        float oo = sigm(og[3]);
        creg = fg * creg + ig * gg;
        h = oo * tanh_fast(creg);

        hH[t & 15][tid] = h;
        if ((t & 15) == 15) {           // flush ring (own-thread data; no barrier needed)
            int t0 = t - 15;
#pragma unroll
            for (int r = 0; r < 16; ++r)
                a.out[(size_t)((t0 + r) * BB + b) * HID + tid] = hH[r][tid];
        }
        __syncthreads();
    }

    a.out[(size_t)TT * BB * HID + (size_t)b * HID + tid] = h;
    a.out[(size_t)TT * BB * HID + (size_t)BB * HID + (size_t)b * HID + tid] = creg;
}

extern "C" void kernel_launch(void* const* d_in, const int* in_sizes, int n_in,
                              void* d_out, int out_size, void* d_ws, size_t ws_size,
                              hipStream_t stream) {
    (void)in_sizes; (void)n_in; (void)out_size; (void)d_ws; (void)ws_size;
    Args ar;
    ar.x = (const float*)d_in[0];
    for (int g = 0; g < 4; ++g) {
        ar.W[g]  = (const float*)d_in[1 + 5 * g];
        ar.bb[g] = (const float*)d_in[2 + 5 * g];
        ar.qp[g] = (const float*)d_in[3 + 5 * g];
        ar.Uo[g] = (const float*)d_in[4 + 5 * g];
        ar.cb[g] = (const float*)d_in[5 + 5 * g];
    }
    ar.out = (float*)d_out;
    qlstm_kernel<<<dim3(BB), dim3(256), 0, stream>>>(ar);
}

// Round 9
// 243.160 us; speedup vs baseline: 1.4747x; 1.0039x over previous
//
#include <hip/hip_runtime.h>
#include <math.h>

#define BB   128
#define TT   64
#define IND  128
#define HID  256
#define CD   384   // comb dim = IND + HID

struct C2 { float x, y; };
__device__ __forceinline__ C2 cmul(C2 a, C2 b) { return {a.x*b.x - a.y*b.y, a.x*b.y + a.y*b.x}; }
__device__ __forceinline__ C2 cadd(C2 a, C2 b) { return {a.x + b.x, a.y + b.y}; }
__device__ __forceinline__ C2 csub(C2 a, C2 b) { return {a.x - b.x, a.y - b.y}; }
__device__ __forceinline__ C2 conjc(C2 a) { return {a.x, -a.y}; }

struct Args {
    const float* x;
    const float* W[4];
    const float* bb[4];
    const float* qp[4];
    const float* Uo[4];
    const float* cb[4];
    float* out;
};

template<int CTRL>
__device__ __forceinline__ int dppmv(int v) {
    return __builtin_amdgcn_update_dpp(v, v, CTRL, 0xF, 0xF, false);
}

// Lane-xor exchange, now ALL-VALU where possible.
//  1,2: quad_perm DPP. 8: row_ror:8 DPP (xor8 == rot8 within 16). [proven R3/R8]
//  4: DPP row_shl:4 / row_shr:4 pair + select. R4's orientation
//     ((tid&4)?shl:shr) is PROVEN WRONG by the R6/R7 A/B (only diff, fail->pass),
//     so the flipped select is correct.
//  16/32: v_permlane{16,32}_swap_b32 via BUILTIN (returns both outputs as
//     distinct SSA values). R4/R5's inline-asm version tied x==y into ONE
//     VGPR (compiler CSE) -> swapped a register with itself -> garbage.
//     Semantics: first[l]=v[l&~N], second[l]=v[l|N] -> (lane&N)?first:second.
template<int M>
__device__ __forceinline__ float lx(float v) {
    int i = __float_as_int(v);
    if constexpr (M == 1)
        return __int_as_float(dppmv<0xB1>(i));            // quad_perm [1,0,3,2]
    else if constexpr (M == 2)
        return __int_as_float(dppmv<0x4E>(i));            // quad_perm [2,3,0,1]
    else if constexpr (M == 4) {
        int a = dppmv<0x104>(i);                          // row_shl:4
        int b = dppmv<0x114>(i);                          // row_shr:4
        return __int_as_float((threadIdx.x & 4) ? b : a); // FLIPPED vs R4 (R4 proven wrong)
    } else if constexpr (M == 8)
        return __int_as_float(dppmv<0x128>(i));           // row_ror:8 == xor8
    else if constexpr (M == 16) {
#if __has_builtin(__builtin_amdgcn_permlane16_swap)
        auto r = __builtin_amdgcn_permlane16_swap(i, i, false, false);
        return __int_as_float((threadIdx.x & 16) ? r[0] : r[1]);
#else
        return __int_as_float(__builtin_amdgcn_ds_swizzle(i, 0x401F));  // xor16 (proven R3)
#endif
    } else {
#if __has_builtin(__builtin_amdgcn_permlane32_swap)
        auto r = __builtin_amdgcn_permlane32_swap(i, i, false, false);
        return __int_as_float((threadIdx.x & 32) ? r[0] : r[1]);
#else
        return __shfl_xor(v, 32);                         // ds_bpermute (proven R2/R3)
#endif
    }
}

__device__ __forceinline__ float rfl(float v) {
    return __int_as_float(__builtin_amdgcn_readfirstlane(__float_as_int(v)));
}
__device__ __forceinline__ float bcast_lane(float v, int srclane) {
    return __int_as_float(__builtin_amdgcn_readlane(__float_as_int(v), srclane));
}
__device__ __forceinline__ float sigm(float x) {
    return __builtin_amdgcn_rcpf(1.f + __expf(-x));
}
__device__ __forceinline__ float tanh_fast(float x) {
    float e = __expf(2.f * x);
    return 1.f - 2.f * __builtin_amdgcn_rcpf(e + 1.f);
}

// SU(2) gate on a lane-bit qubit; u = {ax, ay(sign-baked), bx(sign-baked), by}.
template<int M>
__device__ __forceinline__ void gate_lane(float (&are)[4], float (&aim)[4], const float* u) {
#pragma unroll
    for (int r = 0; r < 4; ++r) {
        float px = lx<M>(are[r]);
        float py = lx<M>(aim[r]);
        float nx = u[0]*are[r] - u[1]*aim[r] + u[2]*px - u[3]*py;
        float ny = u[0]*aim[r] + u[1]*are[r] + u[2]*py + u[3]*px;
        are[r] = nx; aim[r] = ny;
    }
}

// SU(2) gate on a register-bit qubit pair: n0 = a*A0 + b*A1; n1 = -conj(b)*A0 + conj(a)*A1.
__device__ __forceinline__ void gate_pair2(float& a0x, float& a0y, float& a1x, float& a1y,
                                           float ax, float ay, float bx, float by) {
    float n0x = ax*a0x - ay*a0y + bx*a1x - by*a1y;
    float n0y = ax*a0y + ay*a0x + bx*a1y + by*a1x;
    float n1x = -bx*a0x - by*a0y + ax*a1x + ay*a1y;
    float n1y = -bx*a0y + by*a0x + ax*a1y - ay*a1x;
    a0x = n0x; a0y = n0y; a1x = n1x; a1y = n1y;
}

template<int M>
__device__ __forceinline__ void cswapT(float (&are)[4], float (&aim)[4], bool ctrl) {
#pragma unroll
    for (int r = 0; r < 4; ++r) {
        float px = lx<M>(are[r]);
        float py = lx<M>(aim[r]);
        are[r] = ctrl ? px : are[r];
        aim[r] = ctrl ? py : aim[r];
    }
}

__global__ __launch_bounds__(256, 1) void qlstm_kernel(Args a) {
    const int b    = blockIdx.x;
    const int tid  = threadIdx.x;
    const int lane = tid & 63;
    const int wv   = tid >> 6;          // wave id == gate id (f,i,g,o)

    __shared__ float Ax[TT][32];                       // x-part of angles (+bias), all t
    __shared__ __align__(16) float hH[16][HID];        // h history ring (flushed /16 steps)
    __shared__ __align__(16) float4 uab[4][2][8];      // SU(2) (ax,ay,bx,by) per gate
    __shared__ __align__(16) float expL[32];           // <Z_q> all 4 gates

    // ---- angle-stage role: angle a_ang = tid>>3, partial p = tid&7 covers 32 contig h ----
    const int a_ang = tid >> 3, p = tid & 7;
    const int g_ang = a_ang >> 3, q_ang = a_ang & 7;
    float whr[8][4];
    {
        const float* Wg = a.W[g_ang] + q_ang * CD + IND;   // h-part of this W row
#pragma unroll
        for (int k = 0; k < 8; ++k) {
            int base = p * 32 + ((4 * (k + p)) & 31);      // staggered: conflict-free b128
#pragma unroll
            for (int j = 0; j < 4; ++j) whr[k][j] = Wg[base + j];
        }
    }
    // ---- output-stage role: hidden unit j = tid ----
    float ur[4][8], cbr[4];
#pragma unroll
    for (int g = 0; g < 4; ++g) {
#pragma unroll
        for (int k = 0; k < 8; ++k) ur[g][k] = a.Uo[g][tid * 8 + k];
        cbr[g] = a.cb[g][tid];
    }

    // ---- SU(2) parameter unitaries alpha,beta = Rz*Ry*Rx (once) ----
    if (tid < 64) {
        int g = tid >> 4, d = (tid >> 3) & 1, q = tid & 7;
        const float* qp = a.qp[g] + q * 6 + d * 3;
        float s0, c0, s1, c1, s2, c2;
        sincosf(0.5f * qp[0], &s0, &c0);
        sincosf(0.5f * qp[1], &s1, &c1);
        sincosf(0.5f * qp[2], &s2, &c2);
        C2 aX{c0, 0.f}, bX{0.f, -s0};          // Rx
        C2 aY{c1, 0.f}, bY{-s1, 0.f};          // Ry
        C2 aB = csub(cmul(aY, aX), cmul(bY, conjc(bX)));   // Ry∘Rx
        C2 bB = cadd(cmul(aY, bX), cmul(bY, conjc(aX)));
        C2 aZ{c2, -s2};                         // Rz (beta=0)
        C2 al = cmul(aZ, aB), be = cmul(aZ, bB);
        uab[g][d][q] = make_float4(al.x, al.y, be.x, be.y);
    }

    // ---- x-part of angles for all timesteps (once) ----
    for (int rep = 0; rep < 8; ++rep) {
        int idx = rep * 256 + tid;
        int t = idx >> 5, aa = idx & 31;
        int gg = aa >> 3, qq = aa & 7;
        const float4* w4 = (const float4*)(a.W[gg] + qq * CD);
        const float4* x4 = (const float4*)(a.x + (size_t)(t * BB + b) * IND);
        float acc = a.bb[gg][qq];
        for (int e = 0; e < IND / 4; ++e) {
            float4 xv = x4[e], wvv = w4[e];
            acc += xv.x * wvv.x + xv.y * wvv.y + xv.z * wvv.z + xv.w * wvv.w;
        }
        Ax[t][aa] = acc;
    }

    hH[15][tid] = 0.f;                  // h_{-1} = 0 lives at ring row 15
    float creg = 0.f, h = 0.f;
    __syncthreads();

    // ---- bake per-wave unitaries into registers (lane-bit signs applied) ----
    float gA[2][6][4];                  // 48 VGPR: qubits 2..7 (lane bits 5..0)
#pragma unroll
    for (int d = 0; d < 2; ++d)
#pragma unroll
    for (int qi = 0; qi < 6; ++qi) {
        float4 u = uab[wv][d][qi + 2];
        bool bit = (lane >> (5 - qi)) & 1;
        gA[d][qi][0] = u.x;
        gA[d][qi][1] = bit ? -u.y : u.y;
        gA[d][qi][2] = bit ? -u.z : u.z;
        gA[d][qi][3] = u.w;
    }
    float qr[2][2][4];                  // SGPRs: qubits 0,1 (register bits)
#pragma unroll
    for (int d = 0; d < 2; ++d) {
        float4 u0 = uab[wv][d][0], u1 = uab[wv][d][1];
        qr[0][d][0] = rfl(u0.x); qr[0][d][1] = rfl(u0.y);
        qr[0][d][2] = rfl(u0.z); qr[0][d][3] = rfl(u0.w);
        qr[1][d][0] = rfl(u1.x); qr[1][d][1] = rfl(u1.y);
        qr[1][d][2] = rfl(u1.z); qr[1][d][3] = rfl(u1.w);
    }

    for (int t = 0; t < TT; ++t) {
        // ---- angle stage: wave-local; staggered float4 LDS reads, no bank conflicts ----
        const int rowPrev = (t + 15) & 15;
        const float* hrow = hH[rowPrev];
        float ac0 = 0.f, ac1 = 0.f;
#pragma unroll
        for (int k = 0; k < 8; ++k) {
            int base = p * 32 + ((4 * (k + p)) & 31);
            const float4 hv = *reinterpret_cast<const float4*>(&hrow[base]);
            if (k & 1) { ac1 += hv.x*whr[k][0] + hv.y*whr[k][1] + hv.z*whr[k][2] + hv.w*whr[k][3]; }
            else       { ac0 += hv.x*whr[k][0] + hv.y*whr[k][1] + hv.z*whr[k][2] + hv.w*whr[k][3]; }
        }
        float acc = ac0 + ac1;
        acc += lx<1>(acc);
        acc += lx<2>(acc);
        acc += lx<4>(acc);
        float ang = 0.5f * (acc + Ax[t][a_ang]);
        float cA = __cosf(ang), sA = __sinf(ang);
        float cs_c[8], cs_s[8];
#pragma unroll
        for (int q = 0; q < 8; ++q) {
            cs_c[q] = bcast_lane(cA, q * 8);
            cs_s[q] = bcast_lane(sA, q * 8);
        }

        // ---- product-state init: amp = prod_q f_q, tree-multiplied ----
        float are[4], aim[4];
        {
            C2 f[6];
#pragma unroll
            for (int qi = 0; qi < 6; ++qi) {
                bool bit = (lane >> (5 - qi)) & 1;
                f[qi].x = bit ? 0.f : cs_c[qi + 2];
                f[qi].y = bit ? -cs_s[qi + 2] : 0.f;
            }
            C2 c01 = cmul(f[0], f[1]);
            C2 c23 = cmul(f[2], f[3]);
            C2 c45 = cmul(f[4], f[5]);
            C2 com = cmul(cmul(c01, c23), c45);
#pragma unroll
            for (int r = 0; r < 4; ++r) {
                float f1x = (r & 1)  ? 0.f : cs_c[1], f1y = (r & 1)  ? -cs_s[1] : 0.f;
                float f0x = (r >> 1) ? 0.f : cs_c[0], f0y = (r >> 1) ? -cs_s[0] : 0.f;
                C2 t1 = cmul(com, {f1x, f1y});
                are[r] = t1.x * f0x - t1.y * f0y;
                aim[r] = t1.x * f0y + t1.y * f0x;
            }
        }

        // ---- circuit: 2 depths, cross-lane traffic all-VALU ----
#pragma unroll
        for (int d = 0; d < 2; ++d) {
            gate_pair2(are[0], aim[0], are[2], aim[2], qr[0][d][0], qr[0][d][1], qr[0][d][2], qr[0][d][3]);
            gate_pair2(are[1], aim[1], are[3], aim[3], qr[0][d][0], qr[0][d][1], qr[0][d][2], qr[0][d][3]);
            gate_pair2(are[0], aim[0], are[1], aim[1], qr[1][d][0], qr[1][d][1], qr[1][d][2], qr[1][d][3]);
            gate_pair2(are[2], aim[2], are[3], aim[3], qr[1][d][0], qr[1][d][1], qr[1][d][2], qr[1][d][3]);
            gate_lane<32>(are, aim, gA[d][0]);
            gate_lane<16>(are, aim, gA[d][1]);
            gate_lane< 8>(are, aim, gA[d][2]);
            gate_lane< 4>(are, aim, gA[d][3]);
            gate_lane< 2>(are, aim, gA[d][4]);
            gate_lane< 1>(are, aim, gA[d][5]);
            // CNOT chain: (0,1),(1,2),...,(6,7),(7,0)
            { float tx = are[2], ty = aim[2];
              are[2] = are[3]; aim[2] = aim[3]; are[3] = tx; aim[3] = ty; }
            { are[1] = lx<32>(are[1]); aim[1] = lx<32>(aim[1]);
              are[3] = lx<32>(are[3]); aim[3] = lx<32>(aim[3]); }
            cswapT<16>(are, aim, (lane >> 5) & 1);
            cswapT< 8>(are, aim, (lane >> 4) & 1);
            cswapT< 4>(are, aim, (lane >> 3) & 1);
            cswapT< 2>(are, aim, (lane >> 2) & 1);
            cswapT< 1>(are, aim, (lane >> 1) & 1);
            { const bool ctrl = lane & 1;
              float t0x = ctrl ? are[2] : are[0], t0y = ctrl ? aim[2] : aim[0];
              float t2x = ctrl ? are[0] : are[2], t2y = ctrl ? aim[0] : aim[2];
              float t1x = ctrl ? are[3] : are[1], t1y = ctrl ? aim[3] : aim[1];
              float t3x = ctrl ? are[1] : are[3], t3y = ctrl ? aim[1] : aim[3];
              are[0] = t0x; aim[0] = t0y; are[2] = t2x; aim[2] = t2y;
              are[1] = t1x; aim[1] = t1y; are[3] = t3x; aim[3] = t3y; }
        }

        // ---- expvals: multi-output Walsh butterfly (lane 0 ends correct) ----
        float pr[4];
#pragma unroll
        for (int r = 0; r < 4; ++r) pr[r] = are[r]*are[r] + aim[r]*aim[r];
        float s0 = pr[0] + pr[1] - pr[2] - pr[3];   // qubit 0 (reg bit 1)
        float s1 = pr[0] - pr[1] + pr[2] - pr[3];   // qubit 1 (reg bit 0)
        float T  = pr[0] + pr[1] + pr[2] + pr[3];
        float s2, s3, s4, s5, s6, s7;
        { float pT = lx<1>(T);  s7 = T - pT; T += pT;
          s0 += lx<1>(s0); s1 += lx<1>(s1); }
        { float pT = lx<2>(T);  s6 = T - pT; T += pT;
          s0 += lx<2>(s0); s1 += lx<2>(s1); s7 += lx<2>(s7); }
        { float pT = lx<4>(T);  s5 = T - pT; T += pT;
          s0 += lx<4>(s0); s1 += lx<4>(s1); s7 += lx<4>(s7); s6 += lx<4>(s6); }
        { float pT = lx<8>(T);  s4 = T - pT; T += pT;
          s0 += lx<8>(s0); s1 += lx<8>(s1); s7 += lx<8>(s7); s6 += lx<8>(s6); s5 += lx<8>(s5); }
        { float pT = lx<16>(T); s3 = T - pT; T += pT;
          s0 += lx<16>(s0); s1 += lx<16>(s1); s7 += lx<16>(s7); s6 += lx<16>(s6); s5 += lx<16>(s5); s4 += lx<16>(s4); }
        { float pT = lx<32>(T); s2 = T - pT;
          s0 += lx<32>(s0); s1 += lx<32>(s1); s7 += lx<32>(s7); s6 += lx<32>(s6); s5 += lx<32>(s5); s4 += lx<32>(s4); s3 += lx<32>(s3); }
        if (lane == 0) {
            expL[wv*8 + 0] = s0; expL[wv*8 + 1] = s1; expL[wv*8 + 2] = s2; expL[wv*8 + 3] = s3;
            expL[wv*8 + 4] = s4; expL[wv*8 + 5] = s5; expL[wv*8 + 6] = s6; expL[wv*8 + 7] = s7;
        }
        __syncthreads();

        // ---- output projection + LSTM pointwise (thread j = tid) ----
        const float4* eL = (const float4*)expL;
        float og[4];
#pragma unroll
        for (int g = 0; g < 4; ++g) {
            float4 e0 = eL[g*2], e1 = eL[g*2 + 1];
            og[g] = cbr[g]
                  + e0.x*ur[g][0] + e0.y*ur[g][1] + e0.z*ur[g][2] + e0.w*ur[g][3]
                  + e1.x*ur[g][4] + e1.y*ur[g][5] + e1.z*ur[g][6] + e1.w*ur[g][7];
        }
        float fg = sigm(og[0]);
        float ig = sigm(og[1]);
        float gg = tanh_fast(og[2]);
        float oo = sigm(og[3]);
        creg = fg * creg + ig * gg;
        h = oo * tanh_fast(creg);

        hH[t & 15][tid] = h;
        if ((t & 15) == 15) {           // flush ring (own-thread data; no barrier needed)
            int t0 = t - 15;
#pragma unroll
            for (int r = 0; r < 16; ++r)
                a.out[(size_t)((t0 + r) * BB + b) * HID + tid] = hH[r][tid];
        }
        __syncthreads();
    }

    a.out[(size_t)TT * BB * HID + (size_t)b * HID + tid] = h;
    a.out[(size_t)TT * BB * HID + (size_t)BB * HID + (size_t)b * HID + tid] = creg;
}

extern "C" void kernel_launch(void* const* d_in, const int* in_sizes, int n_in,
                              void* d_out, int out_size, void* d_ws, size_t ws_size,
                              hipStream_t stream) {
    (void)in_sizes; (void)n_in; (void)out_size; (void)d_ws; (void)ws_size;
    Args ar;
    ar.x = (const float*)d_in[0];
    for (int g = 0; g < 4; ++g) {
        ar.W[g]  = (const float*)d_in[1 + 5 * g];
        ar.bb[g] = (const float*)d_in[2 + 5 * g];
        ar.qp[g] = (const float*)d_in[3 + 5 * g];
        ar.Uo[g] = (const float*)d_in[4 + 5 * g];
        ar.cb[g] = (const float*)d_in[5 + 5 * g];
    }
    ar.out = (float*)d_out;
    qlstm_kernel<<<dim3(BB), dim3(256), 0, stream>>>(ar);
}

// Round 10
// 156.337 us; speedup vs baseline: 2.2937x; 1.5554x over previous
//
#include <hip/hip_runtime.h>
#include <math.h>

#define BB   128
#define TT   64
#define IND  128
#define HID  256
#define CD   384   // comb dim = IND + HID

struct C2 { float x, y; };
__device__ __forceinline__ C2 cmul(C2 a, C2 b) { return {a.x*b.x - a.y*b.y, a.x*b.y + a.y*b.x}; }
__device__ __forceinline__ C2 cadd(C2 a, C2 b) { return {a.x + b.x, a.y + b.y}; }
__device__ __forceinline__ C2 csub(C2 a, C2 b) { return {a.x - b.x, a.y - b.y}; }
__device__ __forceinline__ C2 conjc(C2 a) { return {a.x, -a.y}; }

struct Args {
    const float* x;
    const float* W[4];
    const float* bb[4];
    const float* qp[4];
    const float* Uo[4];
    const float* cb[4];
    float* out;
};

template<int CTRL>
__device__ __forceinline__ int dppmv(int v) {
    return __builtin_amdgcn_update_dpp(v, v, CTRL, 0xF, 0xF, false);
}

// Lane-xor exchange (R9-proven, all-VALU).
template<int M>
__device__ __forceinline__ float lx(float v) {
    int i = __float_as_int(v);
    if constexpr (M == 1)
        return __int_as_float(dppmv<0xB1>(i));            // quad_perm [1,0,3,2]
    else if constexpr (M == 2)
        return __int_as_float(dppmv<0x4E>(i));            // quad_perm [2,3,0,1]
    else if constexpr (M == 4) {
        int a = dppmv<0x104>(i);                          // row_shl:4
        int b = dppmv<0x114>(i);                          // row_shr:4
        return __int_as_float((threadIdx.x & 4) ? b : a);
    } else if constexpr (M == 8)
        return __int_as_float(dppmv<0x128>(i));           // row_ror:8 == xor8
    else if constexpr (M == 16) {
#if __has_builtin(__builtin_amdgcn_permlane16_swap)
        auto r = __builtin_amdgcn_permlane16_swap(i, i, false, false);
        return __int_as_float((threadIdx.x & 16) ? r[0] : r[1]);
#else
        return __int_as_float(__builtin_amdgcn_ds_swizzle(i, 0x401F));
#endif
    } else {
#if __has_builtin(__builtin_amdgcn_permlane32_swap)
        auto r = __builtin_amdgcn_permlane32_swap(i, i, false, false);
        return __int_as_float((threadIdx.x & 32) ? r[0] : r[1]);
#else
        return __shfl_xor(v, 32);
#endif
    }
}

__device__ __forceinline__ float rfl(float v) {
    return __int_as_float(__builtin_amdgcn_readfirstlane(__float_as_int(v)));
}
__device__ __forceinline__ float bcast_lane(float v, int srclane) {
    return __int_as_float(__builtin_amdgcn_readlane(__float_as_int(v), srclane));
}
__device__ __forceinline__ float sigm(float x) {
    return __builtin_amdgcn_rcpf(1.f + __expf(-x));
}
__device__ __forceinline__ float tanh_fast(float x) {
    float e = __expf(2.f * x);
    return 1.f - 2.f * __builtin_amdgcn_rcpf(e + 1.f);
}
__device__ __forceinline__ float sgnx(float v, unsigned m) {
    return __int_as_float(__float_as_int(v) ^ (int)m);
}

// SU(2) gate on a lane-bit qubit; u = {ax, ay(sign-baked), bx(sign-baked), by}.
template<int M>
__device__ __forceinline__ void gate_lane(float (&are)[4], float (&aim)[4], const float* u) {
#pragma unroll
    for (int r = 0; r < 4; ++r) {
        float px = lx<M>(are[r]);
        float py = lx<M>(aim[r]);
        float nx = u[0]*are[r] - u[1]*aim[r] + u[2]*px - u[3]*py;
        float ny = u[0]*aim[r] + u[1]*are[r] + u[2]*py + u[3]*px;
        are[r] = nx; aim[r] = ny;
    }
}

// SU(2) gate on a register-bit qubit pair.
__device__ __forceinline__ void gate_pair2(float& a0x, float& a0y, float& a1x, float& a1y,
                                           float ax, float ay, float bx, float by) {
    float n0x = ax*a0x - ay*a0y + bx*a1x - by*a1y;
    float n0y = ax*a0y + ay*a0x + bx*a1y + by*a1x;
    float n1x = -bx*a0x - by*a0y + ax*a1x + ay*a1y;
    float n1y = -bx*a0y + by*a0x + ax*a1y - ay*a1x;
    a0x = n0x; a0y = n0y; a1x = n1x; a1y = n1y;
}

template<int M>
__device__ __forceinline__ void cswapT(float (&are)[4], float (&aim)[4], bool ctrl) {
#pragma unroll
    for (int r = 0; r < 4; ++r) {
        float px = lx<M>(are[r]);
        float py = lx<M>(aim[r]);
        are[r] = ctrl ? px : are[r];
        aim[r] = ctrl ? py : aim[r];
    }
}

__global__ __launch_bounds__(256, 1) void qlstm_kernel(Args a) {
    const int b    = blockIdx.x;
    const int tid  = threadIdx.x;
    const int lane = tid & 63;
    const int wv   = tid >> 6;          // wave id == gate id (f,i,g,o)

    __shared__ float Ax[TT][32];                       // x-part of angles (+bias), all t
    __shared__ __align__(16) float hH[16][HID];        // h history ring (flushed /16 steps)
    __shared__ __align__(16) float4 uab[4][2][8];      // SU(2) (ax,ay,bx,by) per gate
    __shared__ __align__(16) float expL[32];           // <Z_q> all 4 gates

    const int a_ang = tid >> 3, p = tid & 7;
    const int g_ang = a_ang >> 3, q_ang = a_ang & 7;
    float whr[8][4];
    {
        const float* Wg = a.W[g_ang] + q_ang * CD + IND;
#pragma unroll
        for (int k = 0; k < 8; ++k) {
            int base = p * 32 + ((4 * (k + p)) & 31);
#pragma unroll
            for (int j = 0; j < 4; ++j) whr[k][j] = Wg[base + j];
        }
    }
    float ur[4][8], cbr[4];
#pragma unroll
    for (int g = 0; g < 4; ++g) {
#pragma unroll
        for (int k = 0; k < 8; ++k) ur[g][k] = a.Uo[g][tid * 8 + k];
        cbr[g] = a.cb[g][tid];
    }

    // ---- SU(2) parameter unitaries alpha,beta = Rz*Ry*Rx (once) ----
    if (tid < 64) {
        int g = tid >> 4, d = (tid >> 3) & 1, q = tid & 7;
        const float* qp = a.qp[g] + q * 6 + d * 3;
        float s0, c0, s1, c1, s2, c2;
        sincosf(0.5f * qp[0], &s0, &c0);
        sincosf(0.5f * qp[1], &s1, &c1);
        sincosf(0.5f * qp[2], &s2, &c2);
        C2 aX{c0, 0.f}, bX{0.f, -s0};
        C2 aY{c1, 0.f}, bY{-s1, 0.f};
        C2 aB = csub(cmul(aY, aX), cmul(bY, conjc(bX)));
        C2 bB = cadd(cmul(aY, bX), cmul(bY, conjc(aX)));
        C2 aZ{c2, -s2};
        C2 al = cmul(aZ, aB), be = cmul(aZ, bB);
        uab[g][d][q] = make_float4(al.x, al.y, be.x, be.y);
    }

    // ---- x-part of angles for all timesteps (once) ----
    for (int rep = 0; rep < 8; ++rep) {
        int idx = rep * 256 + tid;
        int t = idx >> 5, aa = idx & 31;
        int gg = aa >> 3, qq = aa & 7;
        const float4* w4 = (const float4*)(a.W[gg] + qq * CD);
        const float4* x4 = (const float4*)(a.x + (size_t)(t * BB + b) * IND);
        float acc = a.bb[gg][qq];
        for (int e = 0; e < IND / 4; ++e) {
            float4 xv = x4[e], wvv = w4[e];
            acc += xv.x * wvv.x + xv.y * wvv.y + xv.z * wvv.z + xv.w * wvv.w;
        }
        Ax[t][aa] = acc;
    }

    hH[15][tid] = 0.f;
    float creg = 0.f, h = 0.f;
    __syncthreads();

    // ---- d=0 unitaries as uniform registers (for the init fold) ----
    float u0q[8][4];
#pragma unroll
    for (int q = 0; q < 8; ++q) {
        float4 u = uab[wv][0][q];
        u0q[q][0] = rfl(u.x); u0q[q][1] = rfl(u.y);
        u0q[q][2] = rfl(u.z); u0q[q][3] = rfl(u.w);
    }
    // ---- d=1 lane-gate unitaries, sign-baked per lane ----
    float gA[6][4];
#pragma unroll
    for (int qi = 0; qi < 6; ++qi) {
        float4 u = uab[wv][1][qi + 2];
        bool bit = (lane >> (5 - qi)) & 1;
        gA[qi][0] = u.x;
        gA[qi][1] = bit ? -u.y : u.y;
        gA[qi][2] = bit ? -u.z : u.z;
        gA[qi][3] = u.w;
    }
    // ---- d=1 reg-gate unitaries (uniform) ----
    float qr0[4], qr1[4];
    {
        float4 u0 = uab[wv][1][0], u1 = uab[wv][1][1];
        qr0[0] = rfl(u0.x); qr0[1] = rfl(u0.y); qr0[2] = rfl(u0.z); qr0[3] = rfl(u0.w);
        qr1[0] = rfl(u1.x); qr1[1] = rfl(u1.y); qr1[2] = rfl(u1.z); qr1[3] = rfl(u1.w);
    }
    // ---- measurement sign masks: <Z_q> after CNOT chain == pre-chain state
    // measured with parity(p & row_beta(M)); bit7=r>>1, bit6=r&1, bits5..0=lane.
    // q0: B-combo * par(l&63); q1: D; q2..q7: D * par(l&{32,48,56,60,62,63}).
    unsigned sg0, sg2, sg3, sg4, sg5, sg6, sg7;
    {
        auto par31 = [](int v) -> unsigned { return (unsigned)(__popc(v) & 1) << 31; };
        sg0 = par31(lane & 63);
        sg2 = par31(lane & 32);
        sg3 = par31(lane & 48);
        sg4 = par31(lane & 56);
        sg5 = par31(lane & 60);
        sg6 = par31(lane & 62);
        sg7 = sg0;
    }

    for (int t = 0; t < TT; ++t) {
        // ---- angle stage ----
        const int rowPrev = (t + 15) & 15;
        const float* hrow = hH[rowPrev];
        float ac0 = 0.f, ac1 = 0.f;
#pragma unroll
        for (int k = 0; k < 8; ++k) {
            int base = p * 32 + ((4 * (k + p)) & 31);
            const float4 hv = *reinterpret_cast<const float4*>(&hrow[base]);
            if (k & 1) { ac1 += hv.x*whr[k][0] + hv.y*whr[k][1] + hv.z*whr[k][2] + hv.w*whr[k][3]; }
            else       { ac0 += hv.x*whr[k][0] + hv.y*whr[k][1] + hv.z*whr[k][2] + hv.w*whr[k][3]; }
        }
        float acc = ac0 + ac1;
        acc += lx<1>(acc);
        acc += lx<2>(acc);
        acc += lx<4>(acc);
        float ang = 0.5f * (acc + Ax[t][a_ang]);
        float cA = __cosf(ang), sA = __sinf(ang);
        float cs_c[8], cs_s[8];
#pragma unroll
        for (int q = 0; q < 8; ++q) {
            cs_c[q] = bcast_lane(cA, q * 8);
            cs_s[q] = bcast_lane(sA, q * 8);
        }

        // ---- init with d=0 gates FOLDED: per-qubit 2-vector v = U0 . (c, -i s) ----
        // v0 = (ax c + by s, ay c - bx s); v1 = (-bx c - ay s, by c - ax s)
        float v0x[8], v0y[8], v1x[8], v1y[8];
#pragma unroll
        for (int q = 0; q < 8; ++q) {
            float c = cs_c[q], s = cs_s[q];
            float ax = u0q[q][0], ay = u0q[q][1], bx = u0q[q][2], by = u0q[q][3];
            v0x[q] =  ax*c + by*s;
            v0y[q] =  ay*c - bx*s;
            v1x[q] = -bx*c - ay*s;
            v1y[q] =  by*c - ax*s;
        }
        float are[4], aim[4];
        {
            C2 f[6];
#pragma unroll
            for (int qi = 0; qi < 6; ++qi) {
                int q = qi + 2;
                bool bit = (lane >> (5 - qi)) & 1;
                f[qi].x = bit ? v1x[q] : v0x[q];
                f[qi].y = bit ? v1y[q] : v0y[q];
            }
            C2 c01 = cmul(f[0], f[1]);
            C2 c23 = cmul(f[2], f[3]);
            C2 c45 = cmul(f[4], f[5]);
            C2 com = cmul(cmul(c01, c23), c45);
#pragma unroll
            for (int r = 0; r < 4; ++r) {
                C2 fq1 = (r & 1)  ? C2{v1x[1], v1y[1]} : C2{v0x[1], v0y[1]};
                C2 fq0 = (r >> 1) ? C2{v1x[0], v1y[0]} : C2{v0x[0], v0y[0]};
                C2 t1 = cmul(com, fq1);
                C2 t0 = cmul(t1, fq0);
                are[r] = t0.x; aim[r] = t0.y;
            }
        }

        // ---- d=0 CNOT chain (unchanged, proven) ----
        { float tx = are[2], ty = aim[2];
          are[2] = are[3]; aim[2] = aim[3]; are[3] = tx; aim[3] = ty; }
        { are[1] = lx<32>(are[1]); aim[1] = lx<32>(aim[1]);
          are[3] = lx<32>(are[3]); aim[3] = lx<32>(aim[3]); }
        cswapT<16>(are, aim, (lane >> 5) & 1);
        cswapT< 8>(are, aim, (lane >> 4) & 1);
        cswapT< 4>(are, aim, (lane >> 3) & 1);
        cswapT< 2>(are, aim, (lane >> 2) & 1);
        cswapT< 1>(are, aim, (lane >> 1) & 1);
        { const bool ctrl = lane & 1;
          float t0x = ctrl ? are[2] : are[0], t0y = ctrl ? aim[2] : aim[0];
          float t2x = ctrl ? are[0] : are[2], t2y = ctrl ? aim[0] : aim[2];
          float t1x = ctrl ? are[3] : are[1], t1y = ctrl ? aim[3] : aim[1];
          float t3x = ctrl ? are[1] : are[3], t3y = ctrl ? aim[1] : aim[3];
          are[0] = t0x; aim[0] = t0y; are[2] = t2x; aim[2] = t2y;
          are[1] = t1x; aim[1] = t1y; are[3] = t3x; aim[3] = t3y; }

        // ---- d=1 gate layer (unchanged, proven) ----
        gate_pair2(are[0], aim[0], are[2], aim[2], qr0[0], qr0[1], qr0[2], qr0[3]);
        gate_pair2(are[1], aim[1], are[3], aim[3], qr0[0], qr0[1], qr0[2], qr0[3]);
        gate_pair2(are[0], aim[0], are[1], aim[1], qr1[0], qr1[1], qr1[2], qr1[3]);
        gate_pair2(are[2], aim[2], are[3], aim[3], qr1[0], qr1[1], qr1[2], qr1[3]);
        gate_lane<32>(are, aim, gA[0]);
        gate_lane<16>(are, aim, gA[1]);
        gate_lane< 8>(are, aim, gA[2]);
        gate_lane< 4>(are, aim, gA[3]);
        gate_lane< 2>(are, aim, gA[4]);
        gate_lane< 1>(are, aim, gA[5]);

        // ---- expvals: d=1 CNOT chain folded into parity sign masks ----
        float pr[4];
#pragma unroll
        for (int r = 0; r < 4; ++r) pr[r] = are[r]*are[r] + aim[r]*aim[r];
        float Bc = pr[0] - pr[1] + pr[2] - pr[3];   // (-1)^(r&1)
        float Dc = pr[0] - pr[1] - pr[2] + pr[3];   // (-1)^(par(r))
        float z[8];
        z[0] = sgnx(Bc, sg0);
        z[1] = Dc;
        z[2] = sgnx(Dc, sg2);
        z[3] = sgnx(Dc, sg3);
        z[4] = sgnx(Dc, sg4);
        z[5] = sgnx(Dc, sg5);
        z[6] = sgnx(Dc, sg6);
        z[7] = sgnx(Dc, sg7);
#pragma unroll
        for (int q = 0; q < 8; ++q) z[q] += lx<1>(z[q]);
#pragma unroll
        for (int q = 0; q < 8; ++q) z[q] += lx<2>(z[q]);
#pragma unroll
        for (int q = 0; q < 8; ++q) z[q] += lx<4>(z[q]);
#pragma unroll
        for (int q = 0; q < 8; ++q) z[q] += lx<8>(z[q]);
#pragma unroll
        for (int q = 0; q < 8; ++q) z[q] += lx<16>(z[q]);
#pragma unroll
        for (int q = 0; q < 8; ++q) z[q] += lx<32>(z[q]);
        if (lane == 0) {
#pragma unroll
            for (int q = 0; q < 8; ++q) expL[wv*8 + q] = z[q];
        }
        __syncthreads();

        // ---- output projection + LSTM pointwise ----
        const float4* eL = (const float4*)expL;
        float og[4];
#pragma unroll
        for (int g = 0; g < 4; ++g) {
            float4 e0 = eL[g*2], e1 = eL[g*2 + 1];
            og[g] = cbr[g]
                  + e0.x*ur[g][0] + e0.y*ur[g][1] + e0.z*ur[g][2] + e0.w*ur[g][3]
                  + e1.x*ur[g][4] + e1.y*ur[g][5] + e1.z*ur[g][6] + e1.w*ur[g][7];
        }
        float fg = sigm(og[0]);
        float ig = sigm(og[1]);
        float gg = tanh_fast(og[2]);
        float oo = sigm(og[3]);
        creg = fg * creg + ig * gg;
        h = oo * tanh_fast(creg);

        hH[t & 15][tid] = h;
        if ((t & 15) == 15) {
            int t0 = t - 15;
#pragma unroll
            for (int r = 0; r < 16; ++r)
                a.out[(size_t)((t0 + r) * BB + b) * HID + tid] = hH[r][tid];
        }
        __syncthreads();
    }

    a.out[(size_t)TT * BB * HID + (size_t)b * HID + tid] = h;
    a.out[(size_t)TT * BB * HID + (size_t)BB * HID + (size_t)b * HID + tid] = creg;
}

extern "C" void kernel_launch(void* const* d_in, const int* in_sizes, int n_in,
                              void* d_out, int out_size, void* d_ws, size_t ws_size,
                              hipStream_t stream) {
    (void)in_sizes; (void)n_in; (void)out_size; (void)d_ws; (void)ws_size;
    Args ar;
    ar.x = (const float*)d_in[0];
    for (int g = 0; g < 4; ++g) {
        ar.W[g]  = (const float*)d_in[1 + 5 * g];
        ar.bb[g] = (const float*)d_in[2 + 5 * g];
        ar.qp[g] = (const float*)d_in[3 + 5 * g];
        ar.Uo[g] = (const float*)d_in[4 + 5 * g];
        ar.cb[g] = (const float*)d_in[5 + 5 * g];
    }
    ar.out = (float*)d_out;
    qlstm_kernel<<<dim3(BB), dim3(256), 0, stream>>>(ar);
}